// Round 1
// baseline (1410.989 us; speedup 1.0000x reference)
//
#include <hip/hip_runtime.h>
#include <math.h>

// ---------------------------------------------------------------------------
// SpatialGNN: 3x GCN (residual) + 4-head GAT + MLP + log_softmax
// N=100000 nodes, E=1600000 edges, IN=8, HID=64, HEADS=4, OUT=3
//
// Structure:
//   - Build dst-sorted CSR each launch (counts -> scan -> scatter).
//   - GCN uses (A_norm @ X) @ W reordering => fused gather+transform kernels.
//   - GAT uses per-head reordering: aggregate h3 (64-dim) with alpha weights,
//     then transform by Wg head-block. a_src/a_dst come from h3 @ Weff where
//     Weff[k,h] = sum_c Wg[k, h*64+c] * att[h,c]  (precomputed, 64x4).
//   - GAT aggregate + head transform + MLP1 + MLP2 + log_softmax fused,
//     one wave (64 lanes) per node, shfl-based broadcasts (no LDS races).
// ---------------------------------------------------------------------------

__device__ __forceinline__ float leaky02(float v) { return v > 0.f ? v : 0.2f * v; }

// ---- CSR build ------------------------------------------------------------

__global__ void count_kernel(const int* __restrict__ dst, int E, int* __restrict__ counts) {
    int e = blockIdx.x * blockDim.x + threadIdx.x;
    if (e < E) atomicAdd(&counts[dst[e]], 1);
}

__global__ void scan_pass1(const int* __restrict__ counts, int n, int* __restrict__ blockSums) {
    __shared__ int sh[256];
    int base = blockIdx.x * 2048;
    int tid = threadIdx.x;
    int s = 0;
#pragma unroll
    for (int j = 0; j < 8; ++j) {
        int idx = base + tid * 8 + j;
        if (idx < n) s += counts[idx];
    }
    sh[tid] = s;
    __syncthreads();
    for (int off = 128; off > 0; off >>= 1) {
        if (tid < off) sh[tid] += sh[tid + off];
        __syncthreads();
    }
    if (tid == 0) blockSums[blockIdx.x] = sh[0];
}

__global__ void scan_pass2(const int* __restrict__ blockSums, int nb, int* __restrict__ blockOffs) {
    if (threadIdx.x == 0 && blockIdx.x == 0) {
        int run = 0;
        for (int i = 0; i < nb; ++i) { blockOffs[i] = run; run += blockSums[i]; }
    }
}

__global__ void scan_pass3(const int* __restrict__ counts, int n,
                           const int* __restrict__ blockOffs,
                           int* __restrict__ row_ptr, int* __restrict__ cursor,
                           float* __restrict__ dinv) {
    __shared__ int sh[256];
    int base = blockIdx.x * 2048;
    int tid = threadIdx.x;
    int cnt[8];
    int local = 0;
#pragma unroll
    for (int j = 0; j < 8; ++j) {
        int idx = base + tid * 8 + j;
        cnt[j] = (idx < n) ? counts[idx] : 0;
        local += cnt[j];
    }
    sh[tid] = local;
    __syncthreads();
    // Hillis-Steele inclusive scan over 256 thread sums
    for (int off = 1; off < 256; off <<= 1) {
        int v = (tid >= off) ? sh[tid - off] : 0;
        __syncthreads();
        sh[tid] += v;
        __syncthreads();
    }
    int run = blockOffs[blockIdx.x] + sh[tid] - local;  // exclusive prefix for this thread
#pragma unroll
    for (int j = 0; j < 8; ++j) {
        int idx = base + tid * 8 + j;
        if (idx < n) {
            row_ptr[idx] = run;
            cursor[idx] = run;
            dinv[idx] = rsqrtf((float)(cnt[j] + 1));  // +1 self loop
            run += cnt[j];
            if (idx == n - 1) row_ptr[n] = run;
        }
    }
}

__global__ void scatter_kernel(const int* __restrict__ src, const int* __restrict__ dst, int E,
                               int* __restrict__ cursor, int* __restrict__ col_src) {
    int e = blockIdx.x * blockDim.x + threadIdx.x;
    if (e < E) {
        int d = dst[e];
        int pos = atomicAdd(&cursor[d], 1);
        col_src[pos] = src[e];
    }
}

// ---- GCN layer 1: agg(x, 8-dim) @ W1 + b1, ReLU ---------------------------

__global__ void gcn_layer1(const float* __restrict__ x,
                           const float* __restrict__ W1, const float* __restrict__ b1,
                           const int* __restrict__ row_ptr, const int* __restrict__ col_src,
                           const float* __restrict__ dinv, int n,
                           float* __restrict__ hout) {
    int tid = threadIdx.x;
    int lane = tid & 63;
    int wid = tid >> 6;
    int node = blockIdx.x * 4 + wid;
    if (node >= n) return;
    int dim = lane & 7, sub = lane >> 3;  // 8 edge-slots x 8 dims
    float di = dinv[node];
    int beg = row_ptr[node], end = row_ptr[node + 1];
    float acc = (sub == 0) ? di * x[node * 8 + dim] : 0.f;  // self loop term
    for (int e = beg + sub; e < end; e += 8) {
        int s = col_src[e];
        acc += dinv[s] * x[s * 8 + dim];
    }
    acc += __shfl_xor(acc, 8);
    acc += __shfl_xor(acc, 16);
    acc += __shfl_xor(acc, 32);
    acc *= di;  // every lane now holds agg for its dim; lane k<8 holds dim k
    float agg[8];
#pragma unroll
    for (int k = 0; k < 8; ++k) agg[k] = __shfl(acc, k);
    float s = b1[lane];
#pragma unroll
    for (int k = 0; k < 8; ++k) s += agg[k] * W1[k * 64 + lane];
    hout[node * 64 + lane] = fmaxf(s, 0.f);
}

// ---- GCN layer 2/3: hout = hin + relu(agg(hin) @ W + b) -------------------

__global__ void gcn_layer64(const float* __restrict__ hin,
                            const float* __restrict__ W, const float* __restrict__ b,
                            const int* __restrict__ row_ptr, const int* __restrict__ col_src,
                            const float* __restrict__ dinv, int n,
                            float* __restrict__ hout) {
    __shared__ float Wl[64 * 64];
    int tid = threadIdx.x;
    for (int i = tid; i < 4096; i += 256) Wl[i] = W[i];
    __syncthreads();
    int lane = tid & 63, wid = tid >> 6;
    int node = blockIdx.x * 4 + wid;
    if (node >= n) return;
    float di = dinv[node];
    int beg = row_ptr[node], end = row_ptr[node + 1];
    float acc = di * hin[node * 64 + lane];  // self loop (pre-multiplied form)
    for (int e = beg; e < end; ++e) {
        int s = col_src[e];
        acc += dinv[s] * hin[s * 64 + lane];
    }
    acc *= di;
    float sum = b[lane];
#pragma unroll 16
    for (int k = 0; k < 64; ++k) {
        float av = __shfl(acc, k);
        sum += av * Wl[k * 64 + lane];
    }
    hout[node * 64 + lane] = hin[node * 64 + lane] + fmaxf(sum, 0.f);
}

// ---- GAT: effective attention matrices (64x4 each) ------------------------

__global__ void att_eff_kernel(const float* __restrict__ Wg,
                               const float* __restrict__ att_src, const float* __restrict__ att_dst,
                               float* __restrict__ wsrc_eff, float* __restrict__ wdst_eff) {
    int t = threadIdx.x;  // 256 threads
    int k = t >> 2, h = t & 3;
    float ss = 0.f, sd = 0.f;
    for (int c = 0; c < 64; ++c) {
        float w = Wg[k * 256 + h * 64 + c];
        ss += w * att_src[h * 64 + c];
        sd += w * att_dst[h * 64 + c];
    }
    wsrc_eff[k * 4 + h] = ss;
    wdst_eff[k * 4 + h] = sd;
}

// ---- GAT: per-node attention coefficients a_src/a_dst [N,4] ---------------

__global__ void att_coef_kernel(const float* __restrict__ h3,
                                const float* __restrict__ wsrc_eff, const float* __restrict__ wdst_eff,
                                int n, float* __restrict__ a_src, float* __restrict__ a_dst) {
    int tid = threadIdx.x, lane = tid & 63, wid = tid >> 6;
    int node = blockIdx.x * 4 + wid;
    if (node >= n) return;
    float hv = h3[node * 64 + lane];
#pragma unroll
    for (int h = 0; h < 4; ++h) {
        float vs = hv * wsrc_eff[lane * 4 + h];
        float vd = hv * wdst_eff[lane * 4 + h];
#pragma unroll
        for (int m = 32; m > 0; m >>= 1) {
            vs += __shfl_xor(vs, m);
            vd += __shfl_xor(vd, m);
        }
        if (lane == 0) { a_src[node * 4 + h] = vs; a_dst[node * 4 + h] = vd; }
    }
}

// ---- GAT aggregate + head transform + MLP + log_softmax (fused) -----------

__global__ void gat_mlp_kernel(const float* __restrict__ h3,
                               const float* __restrict__ a_src, const float* __restrict__ a_dst,
                               const int* __restrict__ row_ptr, const int* __restrict__ col_src,
                               const float* __restrict__ Wg, const float* __restrict__ bg,
                               const float* __restrict__ wc1, const float* __restrict__ bc1,
                               const float* __restrict__ wc2, const float* __restrict__ bc2,
                               int n, float* __restrict__ out) {
    int tid = threadIdx.x, lane = tid & 63, wid = tid >> 6;
    int node = blockIdx.x * 4 + wid;
    if (node >= n) return;

    float adst[4], se[4];
#pragma unroll
    for (int h = 0; h < 4; ++h) {
        adst[h] = a_dst[node * 4 + h];
        float v = a_src[node * 4 + h] + adst[h];
        se[h] = leaky02(v);  // self-loop edge logit
    }
    int beg = row_ptr[node], end = row_ptr[node + 1];

    // phase 1: segment max per head (lane-parallel over edges)
    float mh[4] = {-1e30f, -1e30f, -1e30f, -1e30f};
    if (lane == 0) {
#pragma unroll
        for (int h = 0; h < 4; ++h) mh[h] = se[h];
    }
    for (int e = beg + lane; e < end; e += 64) {
        int s = col_src[e];
#pragma unroll
        for (int h = 0; h < 4; ++h) {
            float v = leaky02(a_src[s * 4 + h] + adst[h]);
            mh[h] = fmaxf(mh[h], v);
        }
    }
#pragma unroll
    for (int m = 32; m > 0; m >>= 1) {
#pragma unroll
        for (int h = 0; h < 4; ++h) mh[h] = fmaxf(mh[h], __shfl_xor(mh[h], m));
    }

    // phase 2: softmax denominator per head
    float dh[4] = {0.f, 0.f, 0.f, 0.f};
    if (lane == 0) {
#pragma unroll
        for (int h = 0; h < 4; ++h) dh[h] = __expf(se[h] - mh[h]);
    }
    for (int e = beg + lane; e < end; e += 64) {
        int s = col_src[e];
#pragma unroll
        for (int h = 0; h < 4; ++h) {
            float v = leaky02(a_src[s * 4 + h] + adst[h]);
            dh[h] += __expf(v - mh[h]);
        }
    }
#pragma unroll
    for (int m = 32; m > 0; m >>= 1) {
#pragma unroll
        for (int h = 0; h < 4; ++h) dh[h] += __shfl_xor(dh[h], m);
    }
    float rden[4];
#pragma unroll
    for (int h = 0; h < 4; ++h) rden[h] = 1.f / (dh[h] + 1e-16f);

    // phase 3: alpha-weighted aggregation of h3 (lane = channel c)
    float acc[4];
    {
        float hv = h3[node * 64 + lane];
#pragma unroll
        for (int h = 0; h < 4; ++h) acc[h] = __expf(se[h] - mh[h]) * rden[h] * hv;
    }
    for (int e = beg; e < end; ++e) {
        int s = col_src[e];
        float hv = h3[s * 64 + lane];
#pragma unroll
        for (int h = 0; h < 4; ++h) {
            float v = leaky02(a_src[s * 4 + h] + adst[h]);
            acc[h] += __expf(v - mh[h]) * rden[h] * hv;
        }
    }

    // phase 4: h_att[h*64+lane] = bg + sum_k acc_h[k] * Wg[k, h*64+lane]
    float hat[4];
#pragma unroll
    for (int h = 0; h < 4; ++h) hat[h] = bg[h * 64 + lane];
    for (int k = 0; k < 64; ++k) {
#pragma unroll
        for (int h = 0; h < 4; ++h) {
            float av = __shfl(acc[h], k);
            hat[h] += av * Wg[k * 256 + h * 64 + lane];
        }
    }

    // phase 5: z[lane] = relu(bc1 + sum_{h,k} h_att[h*64+k] * wc1[h*64+k, lane])
    float z = bc1[lane];
    for (int k = 0; k < 64; ++k) {
#pragma unroll
        for (int h = 0; h < 4; ++h) {
            float av = __shfl(hat[h], k);
            z += av * wc1[(h * 64 + k) * 64 + lane];
        }
    }
    z = fmaxf(z, 0.f);

    // phase 6: logits (3) + log_softmax
    float p0 = z * wc2[lane * 3 + 0];
    float p1 = z * wc2[lane * 3 + 1];
    float p2 = z * wc2[lane * 3 + 2];
#pragma unroll
    for (int m = 32; m > 0; m >>= 1) {
        p0 += __shfl_xor(p0, m);
        p1 += __shfl_xor(p1, m);
        p2 += __shfl_xor(p2, m);
    }
    float l0 = p0 + bc2[0], l1 = p1 + bc2[1], l2 = p2 + bc2[2];
    float mx = fmaxf(l0, fmaxf(l1, l2));
    float lse = mx + logf(expf(l0 - mx) + expf(l1 - mx) + expf(l2 - mx));
    if (lane == 0) {
        out[node * 3 + 0] = l0 - lse;
        out[node * 3 + 1] = l1 - lse;
        out[node * 3 + 2] = l2 - lse;
    }
}

// ---------------------------------------------------------------------------

extern "C" void kernel_launch(void* const* d_in, const int* in_sizes, int n_in,
                              void* d_out, int out_size, void* d_ws, size_t ws_size,
                              hipStream_t stream) {
    const float* x       = (const float*)d_in[0];
    const int*   ei      = (const int*)d_in[1];
    const float* w1      = (const float*)d_in[2];
    const float* b1      = (const float*)d_in[3];
    const float* w2      = (const float*)d_in[4];
    const float* b2      = (const float*)d_in[5];
    const float* w3      = (const float*)d_in[6];
    const float* b3      = (const float*)d_in[7];
    const float* wg      = (const float*)d_in[8];
    const float* bg      = (const float*)d_in[9];
    const float* att_s   = (const float*)d_in[10];
    const float* att_d   = (const float*)d_in[11];
    const float* wc1     = (const float*)d_in[12];
    const float* bc1     = (const float*)d_in[13];
    const float* wc2     = (const float*)d_in[14];
    const float* bc2     = (const float*)d_in[15];
    float* out = (float*)d_out;

    const int N = in_sizes[0] / 8;
    const int E = in_sizes[1] / 2;
    const int* srcv = ei;
    const int* dstv = ei + E;

    // workspace layout (256B-aligned slabs)
    char* ws = (char*)d_ws;
    size_t off = 0;
    auto alloc = [&](size_t bytes) -> char* {
        char* p = ws + off;
        off += (bytes + 255) & ~(size_t)255;
        return p;
    };
    int*   counts    = (int*)alloc((size_t)N * 4);
    int*   row_ptr   = (int*)alloc((size_t)(N + 1) * 4);
    int*   cursor    = (int*)alloc((size_t)N * 4);
    int*   col_src   = (int*)alloc((size_t)E * 4);
    int*   blockSums = (int*)alloc(4096 * 4);
    int*   blockOffs = (int*)alloc(4096 * 4);
    float* dinv      = (float*)alloc((size_t)N * 4);
    float* a_src     = (float*)alloc((size_t)N * 16);
    float* a_dst     = (float*)alloc((size_t)N * 16);
    float* wse       = (float*)alloc(256 * 4);
    float* wde       = (float*)alloc(256 * 4);
    float* bufA      = (float*)alloc((size_t)N * 64 * 4);
    float* bufB      = (float*)alloc((size_t)N * 64 * 4);
    (void)ws_size; (void)n_in; (void)out_size;

    hipMemsetAsync(counts, 0, (size_t)N * 4, stream);

    const int TPB = 256;
    int gridE = (E + TPB - 1) / TPB;
    count_kernel<<<gridE, TPB, 0, stream>>>(dstv, E, counts);

    int NB = (N + 2047) / 2048;
    scan_pass1<<<NB, TPB, 0, stream>>>(counts, N, blockSums);
    scan_pass2<<<1, 64, 0, stream>>>(blockSums, NB, blockOffs);
    scan_pass3<<<NB, TPB, 0, stream>>>(counts, N, blockOffs, row_ptr, cursor, dinv);
    scatter_kernel<<<gridE, TPB, 0, stream>>>(srcv, dstv, E, cursor, col_src);

    int gridN = (N + 3) / 4;  // 4 waves (nodes) per 256-thread block
    gcn_layer1<<<gridN, TPB, 0, stream>>>(x, w1, b1, row_ptr, col_src, dinv, N, bufA);
    gcn_layer64<<<gridN, TPB, 0, stream>>>(bufA, w2, b2, row_ptr, col_src, dinv, N, bufB);
    gcn_layer64<<<gridN, TPB, 0, stream>>>(bufB, w3, b3, row_ptr, col_src, dinv, N, bufA);

    att_eff_kernel<<<1, TPB, 0, stream>>>(wg, att_s, att_d, wse, wde);
    att_coef_kernel<<<gridN, TPB, 0, stream>>>(bufA, wse, wde, N, a_src, a_dst);
    gat_mlp_kernel<<<gridN, TPB, 0, stream>>>(bufA, a_src, a_dst, row_ptr, col_src,
                                              wg, bg, wc1, bc1, wc2, bc2, N, out);
}

// Round 2
// 1029.889 us; speedup vs baseline: 1.3700x; 1.3700x over previous
//
#include <hip/hip_runtime.h>
#include <math.h>

// ---------------------------------------------------------------------------
// SpatialGNN: 3x GCN (residual) + 4-head GAT + MLP + log_softmax
// N=100000, E=1600000, IN=8, HID=64, HEADS=4, OUT=3
//
// R1 changes vs R0:
//  - Fold Wg@wc1 -> Ccomb[256,64] (+ bcomb): GAT head-transform (phase 4)
//    eliminated (no activation between GAT out and MLP1).
//  - Per-edge attention weights precomputed edge-parallel (exp done once per
//    edge, not once per lane): node_max (monotone leaky trick) -> edge_weight.
//  - gat_fused: 2 nodes per wave in the dense z-loop (halves Ccomb L2 traffic),
//    full unroll -> v_readlane broadcasts.
//  - GCN dense loop fully unrolled (literal-lane shfl).
// ---------------------------------------------------------------------------

__device__ __forceinline__ float leaky02(float v) { return v > 0.f ? v : 0.2f * v; }

// ---- CSR build ------------------------------------------------------------

__global__ void count_kernel(const int* __restrict__ dst, int E, int* __restrict__ counts) {
    int e = blockIdx.x * blockDim.x + threadIdx.x;
    if (e < E) atomicAdd(&counts[dst[e]], 1);
}

__global__ void scan_pass1(const int* __restrict__ counts, int n, int* __restrict__ blockSums) {
    __shared__ int sh[256];
    int base = blockIdx.x * 2048;
    int tid = threadIdx.x;
    int s = 0;
#pragma unroll
    for (int j = 0; j < 8; ++j) {
        int idx = base + tid * 8 + j;
        if (idx < n) s += counts[idx];
    }
    sh[tid] = s;
    __syncthreads();
    for (int off = 128; off > 0; off >>= 1) {
        if (tid < off) sh[tid] += sh[tid + off];
        __syncthreads();
    }
    if (tid == 0) blockSums[blockIdx.x] = sh[0];
}

__global__ void scan_pass2(const int* __restrict__ blockSums, int nb, int* __restrict__ blockOffs) {
    if (threadIdx.x == 0 && blockIdx.x == 0) {
        int run = 0;
        for (int i = 0; i < nb; ++i) { blockOffs[i] = run; run += blockSums[i]; }
    }
}

__global__ void scan_pass3(const int* __restrict__ counts, int n,
                           const int* __restrict__ blockOffs,
                           int* __restrict__ row_ptr, int* __restrict__ cursor,
                           float* __restrict__ dinv) {
    __shared__ int sh[256];
    int base = blockIdx.x * 2048;
    int tid = threadIdx.x;
    int cnt[8];
    int local = 0;
#pragma unroll
    for (int j = 0; j < 8; ++j) {
        int idx = base + tid * 8 + j;
        cnt[j] = (idx < n) ? counts[idx] : 0;
        local += cnt[j];
    }
    sh[tid] = local;
    __syncthreads();
    for (int off = 1; off < 256; off <<= 1) {
        int v = (tid >= off) ? sh[tid - off] : 0;
        __syncthreads();
        sh[tid] += v;
        __syncthreads();
    }
    int run = blockOffs[blockIdx.x] + sh[tid] - local;
#pragma unroll
    for (int j = 0; j < 8; ++j) {
        int idx = base + tid * 8 + j;
        if (idx < n) {
            row_ptr[idx] = run;
            cursor[idx] = run;
            dinv[idx] = rsqrtf((float)(cnt[j] + 1));
            run += cnt[j];
            if (idx == n - 1) row_ptr[n] = run;
        }
    }
}

__global__ void scatter_kernel(const int* __restrict__ src, const int* __restrict__ dst, int E,
                               int* __restrict__ cursor,
                               int* __restrict__ col_src, int* __restrict__ col_dst) {
    int e = blockIdx.x * blockDim.x + threadIdx.x;
    if (e < E) {
        int d = dst[e];
        int pos = atomicAdd(&cursor[d], 1);
        col_src[pos] = src[e];
        col_dst[pos] = d;
    }
}

// ---- GCN layer 1 ----------------------------------------------------------

__global__ void gcn_layer1(const float* __restrict__ x,
                           const float* __restrict__ W1, const float* __restrict__ b1,
                           const int* __restrict__ row_ptr, const int* __restrict__ col_src,
                           const float* __restrict__ dinv, int n,
                           float* __restrict__ hout) {
    int tid = threadIdx.x;
    int lane = tid & 63;
    int wid = tid >> 6;
    int node = blockIdx.x * 4 + wid;
    if (node >= n) return;
    int dim = lane & 7, sub = lane >> 3;
    float di = dinv[node];
    int beg = row_ptr[node], end = row_ptr[node + 1];
    float acc = (sub == 0) ? di * x[node * 8 + dim] : 0.f;
    for (int e = beg + sub; e < end; e += 8) {
        int s = col_src[e];
        acc += dinv[s] * x[s * 8 + dim];
    }
    acc += __shfl_xor(acc, 8);
    acc += __shfl_xor(acc, 16);
    acc += __shfl_xor(acc, 32);
    acc *= di;
    float agg[8];
#pragma unroll
    for (int k = 0; k < 8; ++k) agg[k] = __shfl(acc, k);
    float s = b1[lane];
#pragma unroll
    for (int k = 0; k < 8; ++k) s += agg[k] * W1[k * 64 + lane];
    hout[node * 64 + lane] = fmaxf(s, 0.f);
}

// ---- GCN layer 2/3 --------------------------------------------------------

__global__ void gcn_layer64(const float* __restrict__ hin,
                            const float* __restrict__ W, const float* __restrict__ b,
                            const int* __restrict__ row_ptr, const int* __restrict__ col_src,
                            const float* __restrict__ dinv, int n,
                            float* __restrict__ hout) {
    __shared__ float Wl[64 * 64];
    int tid = threadIdx.x;
    for (int i = tid; i < 4096; i += 256) Wl[i] = W[i];
    __syncthreads();
    int lane = tid & 63, wid = tid >> 6;
    int node = blockIdx.x * 4 + wid;
    if (node >= n) return;
    float di = dinv[node];
    int beg = row_ptr[node], end = row_ptr[node + 1];
    float acc = di * hin[node * 64 + lane];
    int e = beg;
    for (; e + 1 < end; e += 2) {
        int s0 = col_src[e], s1 = col_src[e + 1];
        float d0 = dinv[s0], d1 = dinv[s1];
        float v0 = hin[s0 * 64 + lane], v1 = hin[s1 * 64 + lane];
        acc += d0 * v0 + d1 * v1;
    }
    for (; e < end; ++e) {
        int s = col_src[e];
        acc += dinv[s] * hin[s * 64 + lane];
    }
    acc *= di;
    float sum = b[lane];
#pragma unroll
    for (int k = 0; k < 64; ++k) {
        float av = __shfl(acc, k);
        sum += av * Wl[k * 64 + lane];
    }
    hout[node * 64 + lane] = hin[node * 64 + lane] + fmaxf(sum, 0.f);
}

// ---- GAT precompute: effective attention vectors (64x4) -------------------

__global__ void att_eff_kernel(const float* __restrict__ Wg,
                               const float* __restrict__ att_src, const float* __restrict__ att_dst,
                               float* __restrict__ wsrc_eff, float* __restrict__ wdst_eff) {
    int t = threadIdx.x;
    int k = t >> 2, h = t & 3;
    float ss = 0.f, sd = 0.f;
    for (int c = 0; c < 64; ++c) {
        float w = Wg[k * 256 + h * 64 + c];
        ss += w * att_src[h * 64 + c];
        sd += w * att_dst[h * 64 + c];
    }
    wsrc_eff[k * 4 + h] = ss;
    wdst_eff[k * 4 + h] = sd;
}

// ---- GAT precompute: Ccomb = blockdiag(Wg) @ wc1, bcomb = bc1 + bg @ wc1 --

__global__ void ccomb_kernel(const float* __restrict__ Wg, const float* __restrict__ bg,
                             const float* __restrict__ wc1, const float* __restrict__ bc1,
                             float* __restrict__ Ccomb, float* __restrict__ bcomb) {
    int bid = blockIdx.x;   // 0..256
    int j = threadIdx.x;    // 64 threads
    if (bid < 256) {
        int h = bid >> 6, k = bid & 63;
        float s = 0.f;
        for (int c = 0; c < 64; ++c)
            s += Wg[k * 256 + h * 64 + c] * wc1[(h * 64 + c) * 64 + j];
        Ccomb[bid * 64 + j] = s;   // row index == h*64+k == bid
    } else {
        float s = bc1[j];
        for (int i = 0; i < 256; ++i) s += bg[i] * wc1[i * 64 + j];
        bcomb[j] = s;
    }
}

// ---- GAT: per-node attention coefficients a_src/a_dst [N,4] ---------------

__global__ void att_coef_kernel(const float* __restrict__ h3,
                                const float* __restrict__ wsrc_eff, const float* __restrict__ wdst_eff,
                                int n, float* __restrict__ a_src, float* __restrict__ a_dst) {
    int tid = threadIdx.x, lane = tid & 63, wid = tid >> 6;
    int node = blockIdx.x * 4 + wid;
    if (node >= n) return;
    float hv = h3[node * 64 + lane];
#pragma unroll
    for (int h = 0; h < 4; ++h) {
        float vs = hv * wsrc_eff[lane * 4 + h];
        float vd = hv * wdst_eff[lane * 4 + h];
#pragma unroll
        for (int m = 32; m > 0; m >>= 1) {
            vs += __shfl_xor(vs, m);
            vd += __shfl_xor(vd, m);
        }
        if (lane == 0) { a_src[node * 4 + h] = vs; a_dst[node * 4 + h] = vd; }
    }
}

// ---- GAT: per-node segment max via leaky monotonicity ---------------------
// m[d,h] = leaky(a_dst[d,h] + max over incoming sources (incl self) a_src[s,h])

__global__ void node_max_kernel(const float4* __restrict__ a_src4, const float4* __restrict__ a_dst4,
                                const int* __restrict__ row_ptr, const int* __restrict__ col_src,
                                int n, float4* __restrict__ m4) {
    int tid = threadIdx.x, lane = tid & 63, wid = tid >> 6;
    int node = blockIdx.x * 4 + wid;
    if (node >= n) return;
    float4 s0 = a_src4[node];
    float mx0 = s0.x, mx1 = s0.y, mx2 = s0.z, mx3 = s0.w;
    int beg = row_ptr[node], end = row_ptr[node + 1];
    for (int e = beg + lane; e < end; e += 64) {
        int s = col_src[e];
        float4 a = a_src4[s];
        mx0 = fmaxf(mx0, a.x); mx1 = fmaxf(mx1, a.y);
        mx2 = fmaxf(mx2, a.z); mx3 = fmaxf(mx3, a.w);
    }
#pragma unroll
    for (int m = 32; m > 0; m >>= 1) {
        mx0 = fmaxf(mx0, __shfl_xor(mx0, m));
        mx1 = fmaxf(mx1, __shfl_xor(mx1, m));
        mx2 = fmaxf(mx2, __shfl_xor(mx2, m));
        mx3 = fmaxf(mx3, __shfl_xor(mx3, m));
    }
    if (lane == 0) {
        float4 ad = a_dst4[node];
        float4 mm;
        mm.x = leaky02(mx0 + ad.x);
        mm.y = leaky02(mx1 + ad.y);
        mm.z = leaky02(mx2 + ad.z);
        mm.w = leaky02(mx3 + ad.w);
        m4[node] = mm;
    }
}

// ---- GAT: edge-parallel unnormalized weights ------------------------------

__global__ void edge_weight_kernel(const int* __restrict__ col_src, const int* __restrict__ col_dst,
                                   const float4* __restrict__ a_src4, const float4* __restrict__ a_dst4,
                                   const float4* __restrict__ m4, int E,
                                   float4* __restrict__ wts4) {
    int p = blockIdx.x * blockDim.x + threadIdx.x;
    if (p >= E) return;
    int s = col_src[p], d = col_dst[p];
    float4 as = a_src4[s], ad = a_dst4[d], mm = m4[d];
    float4 w;
    w.x = __expf(leaky02(as.x + ad.x) - mm.x);
    w.y = __expf(leaky02(as.y + ad.y) - mm.y);
    w.z = __expf(leaky02(as.z + ad.z) - mm.z);
    w.w = __expf(leaky02(as.w + ad.w) - mm.w);
    wts4[p] = w;
}

// ---- GAT aggregate + folded MLP + log_softmax (2 nodes per wave) ----------

__global__ void gat_fused(const float* __restrict__ hfeat,
                          const float4* __restrict__ a_src4, const float4* __restrict__ a_dst4,
                          const float4* __restrict__ m4,
                          const int* __restrict__ row_ptr, const int* __restrict__ col_src,
                          const float4* __restrict__ wts4,
                          const float* __restrict__ Ccomb, const float* __restrict__ bcomb,
                          const float* __restrict__ wc2, const float* __restrict__ bc2,
                          int n, float* __restrict__ out) {
    int tid = threadIdx.x, lane = tid & 63, wid = tid >> 6;
    int node0 = (blockIdx.x * 4 + wid) * 2;
    if (node0 >= n) return;
    int nnodes = (node0 + 1 < n) ? 2 : 1;

    float accn[2][4];
#pragma unroll
    for (int h = 0; h < 4; ++h) { accn[1][h] = 0.f; }

    for (int j = 0; j < nnodes; ++j) {
        int node = node0 + j;
        float4 asf = a_src4[node], adf = a_dst4[node], mm = m4[node];
        float ws0 = __expf(leaky02(asf.x + adf.x) - mm.x);
        float ws1 = __expf(leaky02(asf.y + adf.y) - mm.y);
        float ws2 = __expf(leaky02(asf.z + adf.z) - mm.z);
        float ws3 = __expf(leaky02(asf.w + adf.w) - mm.w);
        float hv = hfeat[node * 64 + lane];
        float a0 = ws0 * hv, a1 = ws1 * hv, a2 = ws2 * hv, a3 = ws3 * hv;
        float d0 = ws0, d1 = ws1, d2 = ws2, d3 = ws3;
        int beg = row_ptr[node], end = row_ptr[node + 1];
        int e = beg;
        for (; e + 3 < end; e += 4) {
            int s0 = col_src[e], s1 = col_src[e + 1], s2 = col_src[e + 2], s3 = col_src[e + 3];
            float4 w0 = wts4[e], w1 = wts4[e + 1], w2 = wts4[e + 2], w3 = wts4[e + 3];
            float h0 = hfeat[s0 * 64 + lane], h1v = hfeat[s1 * 64 + lane];
            float h2v = hfeat[s2 * 64 + lane], h3v = hfeat[s3 * 64 + lane];
            a0 += w0.x * h0 + w1.x * h1v + w2.x * h2v + w3.x * h3v;
            a1 += w0.y * h0 + w1.y * h1v + w2.y * h2v + w3.y * h3v;
            a2 += w0.z * h0 + w1.z * h1v + w2.z * h2v + w3.z * h3v;
            a3 += w0.w * h0 + w1.w * h1v + w2.w * h2v + w3.w * h3v;
            d0 += w0.x + w1.x + w2.x + w3.x;
            d1 += w0.y + w1.y + w2.y + w3.y;
            d2 += w0.z + w1.z + w2.z + w3.z;
            d3 += w0.w + w1.w + w2.w + w3.w;
        }
        for (; e < end; ++e) {
            int s = col_src[e];
            float4 w = wts4[e];
            float hvv = hfeat[s * 64 + lane];
            a0 += w.x * hvv; a1 += w.y * hvv; a2 += w.z * hvv; a3 += w.w * hvv;
            d0 += w.x; d1 += w.y; d2 += w.z; d3 += w.w;
        }
        accn[j][0] = a0 / (d0 + 1e-16f);
        accn[j][1] = a1 / (d1 + 1e-16f);
        accn[j][2] = a2 / (d2 + 1e-16f);
        accn[j][3] = a3 / (d3 + 1e-16f);
    }

    // z[j][lane] = relu(bcomb + sum_{h,k} accn[j][h](k) * Ccomb[(h*64+k)*64+lane])
    float z0 = bcomb[lane], z1 = z0;
#pragma unroll
    for (int k = 0; k < 64; ++k) {
#pragma unroll
        for (int h = 0; h < 4; ++h) {
            float c = Ccomb[(h * 64 + k) * 64 + lane];
            z0 += __shfl(accn[0][h], k) * c;
            z1 += __shfl(accn[1][h], k) * c;
        }
    }
    z0 = fmaxf(z0, 0.f);
    z1 = fmaxf(z1, 0.f);

    // logits + log_softmax, both nodes
    float w20 = wc2[lane * 3 + 0], w21 = wc2[lane * 3 + 1], w22 = wc2[lane * 3 + 2];
    float p0 = z0 * w20, p1 = z0 * w21, p2 = z0 * w22;
    float q0 = z1 * w20, q1 = z1 * w21, q2 = z1 * w22;
#pragma unroll
    for (int m = 32; m > 0; m >>= 1) {
        p0 += __shfl_xor(p0, m); p1 += __shfl_xor(p1, m); p2 += __shfl_xor(p2, m);
        q0 += __shfl_xor(q0, m); q1 += __shfl_xor(q1, m); q2 += __shfl_xor(q2, m);
    }
    if (lane == 0) {
        {
            float l0 = p0 + bc2[0], l1 = p1 + bc2[1], l2 = p2 + bc2[2];
            float mx = fmaxf(l0, fmaxf(l1, l2));
            float lse = mx + logf(expf(l0 - mx) + expf(l1 - mx) + expf(l2 - mx));
            out[node0 * 3 + 0] = l0 - lse;
            out[node0 * 3 + 1] = l1 - lse;
            out[node0 * 3 + 2] = l2 - lse;
        }
        if (nnodes == 2) {
            float l0 = q0 + bc2[0], l1 = q1 + bc2[1], l2 = q2 + bc2[2];
            float mx = fmaxf(l0, fmaxf(l1, l2));
            float lse = mx + logf(expf(l0 - mx) + expf(l1 - mx) + expf(l2 - mx));
            out[(node0 + 1) * 3 + 0] = l0 - lse;
            out[(node0 + 1) * 3 + 1] = l1 - lse;
            out[(node0 + 1) * 3 + 2] = l2 - lse;
        }
    }
}

// ---------------------------------------------------------------------------

extern "C" void kernel_launch(void* const* d_in, const int* in_sizes, int n_in,
                              void* d_out, int out_size, void* d_ws, size_t ws_size,
                              hipStream_t stream) {
    const float* x       = (const float*)d_in[0];
    const int*   ei      = (const int*)d_in[1];
    const float* w1      = (const float*)d_in[2];
    const float* b1      = (const float*)d_in[3];
    const float* w2      = (const float*)d_in[4];
    const float* b2      = (const float*)d_in[5];
    const float* w3      = (const float*)d_in[6];
    const float* b3      = (const float*)d_in[7];
    const float* wg      = (const float*)d_in[8];
    const float* bg      = (const float*)d_in[9];
    const float* att_s   = (const float*)d_in[10];
    const float* att_d   = (const float*)d_in[11];
    const float* wc1     = (const float*)d_in[12];
    const float* bc1     = (const float*)d_in[13];
    const float* wc2     = (const float*)d_in[14];
    const float* bc2     = (const float*)d_in[15];
    float* out = (float*)d_out;

    const int N = in_sizes[0] / 8;
    const int E = in_sizes[1] / 2;
    const int* srcv = ei;
    const int* dstv = ei + E;

    char* ws = (char*)d_ws;
    size_t off = 0;
    auto alloc = [&](size_t bytes) -> char* {
        char* p = ws + off;
        off += (bytes + 255) & ~(size_t)255;
        return p;
    };
    int*   counts    = (int*)alloc((size_t)N * 4);
    int*   row_ptr   = (int*)alloc((size_t)(N + 1) * 4);
    int*   cursor    = (int*)alloc((size_t)N * 4);
    int*   col_src   = (int*)alloc((size_t)E * 4);
    int*   col_dst   = (int*)alloc((size_t)E * 4);
    int*   blockSums = (int*)alloc(4096 * 4);
    int*   blockOffs = (int*)alloc(4096 * 4);
    float* dinv      = (float*)alloc((size_t)N * 4);
    float* a_src     = (float*)alloc((size_t)N * 16);
    float* a_dst     = (float*)alloc((size_t)N * 16);
    float* m4        = (float*)alloc((size_t)N * 16);
    float* wse       = (float*)alloc(256 * 4);
    float* wde       = (float*)alloc(256 * 4);
    float* Ccomb     = (float*)alloc(256 * 64 * 4);
    float* bcomb     = (float*)alloc(64 * 4);
    float* bufA      = (float*)alloc((size_t)N * 64 * 4);
    float* bufB      = (float*)alloc((size_t)N * 64 * 4);
    float* wts       = bufB;  // reuse: bufB is dead after gcn layer 3
    (void)ws_size; (void)n_in; (void)out_size;

    hipMemsetAsync(counts, 0, (size_t)N * 4, stream);

    const int TPB = 256;
    int gridE = (E + TPB - 1) / TPB;
    count_kernel<<<gridE, TPB, 0, stream>>>(dstv, E, counts);

    int NB = (N + 2047) / 2048;
    scan_pass1<<<NB, TPB, 0, stream>>>(counts, N, blockSums);
    scan_pass2<<<1, 64, 0, stream>>>(blockSums, NB, blockOffs);
    scan_pass3<<<NB, TPB, 0, stream>>>(counts, N, blockOffs, row_ptr, cursor, dinv);
    scatter_kernel<<<gridE, TPB, 0, stream>>>(srcv, dstv, E, cursor, col_src, col_dst);

    // weight-only precomputes (independent of node features)
    att_eff_kernel<<<1, TPB, 0, stream>>>(wg, att_s, att_d, wse, wde);
    ccomb_kernel<<<257, 64, 0, stream>>>(wg, bg, wc1, bc1, Ccomb, bcomb);

    int gridN = (N + 3) / 4;  // 4 waves (nodes) per 256-thread block
    gcn_layer1<<<gridN, TPB, 0, stream>>>(x, w1, b1, row_ptr, col_src, dinv, N, bufA);
    gcn_layer64<<<gridN, TPB, 0, stream>>>(bufA, w2, b2, row_ptr, col_src, dinv, N, bufB);
    gcn_layer64<<<gridN, TPB, 0, stream>>>(bufB, w3, b3, row_ptr, col_src, dinv, N, bufA);

    att_coef_kernel<<<gridN, TPB, 0, stream>>>(bufA, wse, wde, N, a_src, a_dst);
    node_max_kernel<<<gridN, TPB, 0, stream>>>((const float4*)a_src, (const float4*)a_dst,
                                               row_ptr, col_src, N, (float4*)m4);
    edge_weight_kernel<<<gridE, TPB, 0, stream>>>(col_src, col_dst,
                                                  (const float4*)a_src, (const float4*)a_dst,
                                                  (const float4*)m4, E, (float4*)wts);

    int gridG = (N / 2 + 3) / 4;  // 2 nodes per wave, 4 waves per block
    gat_fused<<<gridG, TPB, 0, stream>>>(bufA, (const float4*)a_src, (const float4*)a_dst,
                                         (const float4*)m4, row_ptr, col_src,
                                         (const float4*)wts, Ccomb, bcomb,
                                         wc2, bc2, N, out);
}